// Round 7
// baseline (65.375 us; speedup 1.0000x reference)
//
#include <hip/hip_runtime.h>

// K-manifold AE cluster objective, fused, bf16-MFMA GEMM.
// out = mean_b min_k [ ||x_b||^2 - 2 w.z + z^T G z + lamb*reg_k ]
// GEMM: Y[16384][320] = X[16384][512] @ W[512][320] via pre-packed B fragments.
// Round 7: BM=16, 1024 blocks, ~30KB LDS -> 4-5 blocks/CU; latency hidden by TLP.

#define KCLUST   16
#define DAMB     512
#define DLAT     10
#define BATCH    16384
#define NC       320
#define LAMBDA   0.01f

#define BM       16            // batch rows per block (1 m-tile)
#define NTHREADS 256           // 4 waves, each owns 5 n-tiles
#define NKS      16            // 512/32 k-steps
#define NNT      20            // 320/16 n-tiles
#define YS       325           // padded Y row stride (floats)
#define NBLK     (BATCH / BM)  // 1024
#define PF       2             // B prefetch ring depth

typedef __attribute__((ext_vector_type(8))) short short8;
typedef __attribute__((ext_vector_type(4))) float f32x4;

__device__ inline short f2bf(float f) {
    unsigned u = __builtin_bit_cast(unsigned, f);
    unsigned r = (u + 0x7FFFu + ((u >> 16) & 1u)) >> 16;
    return (short)r;
}

// ---------------- setup: blocks 0..79 pack W frags; 80..95 compute G/lreg; zero cnt
// wpack[ks][nt][lane][8]: lane l holds B[k = ks*32 + (l>>4)*8 + j][col = nt*16 + (l&15)]
__global__ __launch_bounds__(256) void setup_k(const float* __restrict__ Us,
                                               const float* __restrict__ Vs,
                                               short* __restrict__ wpack,
                                               float* __restrict__ G,
                                               float* __restrict__ lreg,
                                               unsigned* __restrict__ cnt) {
    int b = blockIdx.x;
    int tid = threadIdx.x;
    if (b == 0 && tid == 0)
        __hip_atomic_store(cnt, 0u, __ATOMIC_RELEASE, __HIP_MEMORY_SCOPE_AGENT);
    if (b < 80) {
        int idx  = b * 256 + tid;                  // [0, 16*20*64)
        int ks   = idx / (NNT * 64);
        int rem  = idx % (NNT * 64);
        int nt   = rem / 64;
        int lane = rem % 64;
        int col  = nt * 16 + (lane & 15);
        int cl   = col / 20;
        int c    = col % 20;
        short8 sv;
#pragma unroll
        for (int j = 0; j < 8; ++j) {
            int k = ks * 32 + (lane >> 4) * 8 + j;
            float v;
            if (c < DLAT) v = Vs[(size_t)cl * DLAT * DAMB + c * DAMB + k];
            else          v = Us[(size_t)cl * DAMB * DLAT + k * DLAT + (c - DLAT)];
            sv[j] = f2bf(v);
        }
        *(short8*)&wpack[(size_t)idx * 8] = sv;
    } else {
        __shared__ float red[256];
        int k = b - 80;
        const float* Uk = Us + (size_t)k * DAMB * DLAT;
        const float* Vk = Vs + (size_t)k * DLAT * DAMB;
        float s = 0.f;
        for (int i = tid; i < DAMB * DLAT; i += 256) {
            float a = Uk[i], bb = Vk[i];
            s += a * a + bb * bb;
        }
        red[tid] = s;
        __syncthreads();
        for (int st = 128; st > 0; st >>= 1) {
            if (tid < st) red[tid] += red[tid + st];
            __syncthreads();
        }
        if (tid == 0) lreg[k] = LAMBDA * 0.5f * red[0];
        if (tid < DLAT * DLAT) {
            int i = tid / DLAT, j = tid % DLAT;
            float g = 0.f;
            for (int Dv = 0; Dv < DAMB; ++Dv)
                g += Uk[Dv * DLAT + i] * Uk[Dv * DLAT + j];
            G[k * 100 + tid] = g;
        }
    }
}

// ---------------- main kernel
__global__ __launch_bounds__(NTHREADS, 4) void main_k(const float* __restrict__ x,
                                                      const short* __restrict__ wpack,
                                                      const float* __restrict__ G,
                                                      const float* __restrict__ lreg,
                                                      float* __restrict__ parts,
                                                      unsigned* __restrict__ cnt,
                                                      float* __restrict__ out) {
    __shared__ __align__(16) char uni[BM * YS * 4];   // 20.8 KB: A frags, then Y
    __shared__ float Gs[KCLUST * 100];                // 6.4 KB
    __shared__ float lregs[KCLUST];
    __shared__ float rsqp[BM][16];
    __shared__ float rowsq_s[BM];
    __shared__ float objl[BM][17];
    __shared__ float red[NTHREADS];
    __shared__ int   isLast;

    short* a_lds = (short*)uni;                 // [ks][lane][8], 16 KB
    float* y     = (float*)uni;                 // [BM][YS]

    const int tid  = threadIdx.x;
    const int lane = tid & 63;
    const int wv   = tid >> 6;                  // 0..3 = n-strip (5 n-tiles each)
    const int row0 = blockIdx.x * BM;

    // ---- stage A (fp32 -> bf16, fragment order) + exact fp32 rowsq; stage G
    {
        const int srow = tid >> 4;              // 0..15
        const int sc   = tid & 15;              // 0..15
        const float* xr = x + (size_t)(row0 + srow) * DAMB;
        float rs = 0.f;
#pragma unroll
        for (int i = 0; i < 4; ++i) {
            int g = sc + 16 * i;                // 8-float group, 0..63
            float4 v0 = *(const float4*)(xr + g * 8);
            float4 v1 = *(const float4*)(xr + g * 8 + 4);
            rs += v0.x * v0.x + v0.y * v0.y + v0.z * v0.z + v0.w * v0.w
                + v1.x * v1.x + v1.y * v1.y + v1.z * v1.z + v1.w * v1.w;
            short8 sv;
            sv[0] = f2bf(v0.x); sv[1] = f2bf(v0.y); sv[2] = f2bf(v0.z); sv[3] = f2bf(v0.w);
            sv[4] = f2bf(v1.x); sv[5] = f2bf(v1.y); sv[6] = f2bf(v1.z); sv[7] = f2bf(v1.w);
            int ks = g >> 2, lh = g & 3;
            int ln = (lh << 4) | srow;
            *(short8*)&a_lds[(ks * 64 + ln) * 8] = sv;
        }
        rsqp[srow][sc] = rs;
    }
    for (int i = tid; i < KCLUST * 100; i += NTHREADS) Gs[i] = G[i];
    if (tid < KCLUST) lregs[tid] = lreg[tid];
    __syncthreads();
    if (tid < BM) {
        float s = 0.f;
#pragma unroll
        for (int j = 0; j < 16; ++j) s += rsqp[tid][j];
        rowsq_s[tid] = s;
    }

    // ---- K loop: barrier-free; B from L2 via small register ring; A from LDS
    f32x4 acc[5];
#pragma unroll
    for (int j = 0; j < 5; ++j) acc[j] = (f32x4)0.f;

    const short8* wp8 = (const short8*)wpack;
    short8 bbuf[PF][5];
#pragma unroll
    for (int p = 0; p < PF; ++p)
#pragma unroll
        for (int j = 0; j < 5; ++j)
            bbuf[p][j] = wp8[(p * NNT + wv * 5 + j) * 64 + lane];

#pragma unroll
    for (int ks = 0; ks < NKS; ++ks) {
        short8 b0 = bbuf[ks & (PF - 1)][0], b1 = bbuf[ks & (PF - 1)][1],
               b2 = bbuf[ks & (PF - 1)][2], b3 = bbuf[ks & (PF - 1)][3],
               b4 = bbuf[ks & (PF - 1)][4];
        if (ks + PF < NKS) {
#pragma unroll
            for (int j = 0; j < 5; ++j)
                bbuf[ks & (PF - 1)][j] = wp8[((ks + PF) * NNT + wv * 5 + j) * 64 + lane];
        }
        short8 a0 = *(short8*)&a_lds[(ks * 64 + lane) * 8];
        acc[0] = __builtin_amdgcn_mfma_f32_16x16x32_bf16(a0, b0, acc[0], 0, 0, 0);
        acc[1] = __builtin_amdgcn_mfma_f32_16x16x32_bf16(a0, b1, acc[1], 0, 0, 0);
        acc[2] = __builtin_amdgcn_mfma_f32_16x16x32_bf16(a0, b2, acc[2], 0, 0, 0);
        acc[3] = __builtin_amdgcn_mfma_f32_16x16x32_bf16(a0, b3, acc[3], 0, 0, 0);
        acc[4] = __builtin_amdgcn_mfma_f32_16x16x32_bf16(a0, b4, acc[4], 0, 0, 0);
    }
    __syncthreads();                     // a_lds dead; uni becomes Y

    // ---- write Y tile. C/D layout: col = lane&15, row = (lane>>4)*4 + r
    {
        int rowb = (lane >> 4) * 4;
#pragma unroll
        for (int j = 0; j < 5; ++j) {
            int colb = (wv * 5 + j) * 16 + (lane & 15);
#pragma unroll
            for (int r = 0; r < 4; ++r)
                y[(rowb + r) * YS + colb] = acc[j][r];
        }
    }
    __syncthreads();

    // ---- per-(row,k) objective: one item per thread; tid>>4 groups share kk
    {
        int kk  = tid >> 4;                      // 0..15
        int row = tid & 15;                      // 0..15
        const float* yy = y + row * YS + kk * 20;
        float z[DLAT], w[DLAT];
#pragma unroll
        for (int i = 0; i < DLAT; ++i) { z[i] = yy[i]; w[i] = yy[DLAT + i]; }
        const float* Gk = Gs + kk * 100;
        float s = 0.f, wz = 0.f;
#pragma unroll
        for (int i = 0; i < DLAT; ++i) {
            float gz = 0.f;
#pragma unroll
            for (int j = 0; j < DLAT; ++j) gz = fmaf(Gk[i * DLAT + j], z[j], gz);
            s  = fmaf(z[i], gz, s);
            wz = fmaf(w[i], z[i], wz);
        }
        objl[row][kk] = s - 2.f * wz + lregs[kk];
    }
    __syncthreads();

    // ---- per-row min + wave-0 shuffle reduce (no barriers)
    if (wv == 0) {
        float v = 0.f;
        if (lane < BM) {
            float m = objl[lane][0];
#pragma unroll
            for (int k = 1; k < KCLUST; ++k) m = fminf(m, objl[lane][k]);
            v = m + rowsq_s[lane];
        }
#pragma unroll
        for (int off = 8; off > 0; off >>= 1) v += __shfl_down(v, off);
        if (lane == 0) {
            __hip_atomic_store(&parts[blockIdx.x], v, __ATOMIC_RELEASE,
                               __HIP_MEMORY_SCOPE_AGENT);
            unsigned prev = __hip_atomic_fetch_add(cnt, 1u, __ATOMIC_ACQ_REL,
                                                   __HIP_MEMORY_SCOPE_AGENT);
            isLast = (prev == NBLK - 1);
        }
    }
    __syncthreads();

    // ---- last block reduces all 1024 partials (fixed-order tree => deterministic)
    if (isLast) {
        float s = 0.f;
#pragma unroll
        for (int q = 0; q < NBLK / NTHREADS; ++q)
            s += __hip_atomic_load(&parts[tid + q * NTHREADS], __ATOMIC_RELAXED,
                                   __HIP_MEMORY_SCOPE_AGENT);
        red[tid] = s;
        __syncthreads();
        for (int st = NTHREADS / 2; st > 0; st >>= 1) {
            if (tid < st) red[tid] += red[tid + st];
            __syncthreads();
        }
        if (tid == 0) out[0] = red[0] * (1.0f / BATCH);
    }
}

extern "C" void kernel_launch(void* const* d_in, const int* in_sizes, int n_in,
                              void* d_out, int out_size, void* d_ws, size_t ws_size,
                              hipStream_t stream) {
    const float* x  = (const float*)d_in[0];   // 16384 x 512
    const float* Us = (const float*)d_in[1];   // 16 x 512 x 10
    const float* Vs = (const float*)d_in[2];   // 16 x 10 x 512
    float* out = (float*)d_out;

    // workspace: wpack[20480*8] shorts (320KB) | G[1600] | lreg[16] | parts[1024] | cnt
    short* wpack   = (short*)d_ws;
    float* G       = (float*)(wpack + NKS * NNT * 64 * 8);
    float* lreg    = G + KCLUST * 100;
    float* parts   = lreg + KCLUST;
    unsigned* cnt  = (unsigned*)(parts + NBLK);

    setup_k<<<96, 256, 0, stream>>>(Us, Vs, wpack, G, lreg, cnt);
    main_k<<<NBLK, NTHREADS, 0, stream>>>(x, wpack, G, lreg, parts, cnt, out);
}

// Round 8
// 48.643 us; speedup vs baseline: 1.3440x; 1.3440x over previous
//
#include <hip/hip_runtime.h>

// K-manifold AE cluster objective, fused, bf16-MFMA GEMM.
// out = mean_b min_k [ ||x_b||^2 - 2 w.z + z^T G z + lamb*reg_k ]
// GEMM: Y[16384][320] = X[16384][512] @ W[512][320] via pre-packed B fragments.
// Round 8: inline-asm B loads + counted vmcnt ring (compiler cannot sink these).

#define KCLUST   16
#define DAMB     512
#define DLAT     10
#define BATCH    16384
#define NC       320
#define LAMBDA   0.01f

#define BM       32            // batch rows per block (2 m-tiles)
#define NTHREADS 256           // 4 waves, each: 2 m-tiles x 5 n-frags
#define NKS      16            // 512/32 k-steps
#define NNT      20            // 320/16 n-tiles
#define YS       325           // padded Y row stride (floats)
#define NBLK     (BATCH / BM)  // 512

typedef __attribute__((ext_vector_type(8))) short short8;
typedef __attribute__((ext_vector_type(4))) float f32x4;

__device__ inline short f2bf(float f) {
    unsigned u = __builtin_bit_cast(unsigned, f);
    unsigned r = (u + 0x7FFFu + ((u >> 16) & 1u)) >> 16;
    return (short)r;
}

// ---------------- setup: blocks 0..79 pack W frags; 80..95 compute G/lreg; zero cnt
// wpack[ks][nt][lane][8]: lane l holds B[k = ks*32 + (l>>4)*8 + j][col = nt*16 + (l&15)]
__global__ __launch_bounds__(256) void setup_k(const float* __restrict__ Us,
                                               const float* __restrict__ Vs,
                                               short* __restrict__ wpack,
                                               float* __restrict__ G,
                                               float* __restrict__ lreg,
                                               unsigned* __restrict__ cnt) {
    int b = blockIdx.x;
    int tid = threadIdx.x;
    if (b == 0 && tid == 0)
        __hip_atomic_store(cnt, 0u, __ATOMIC_RELEASE, __HIP_MEMORY_SCOPE_AGENT);
    if (b < 80) {
        int idx  = b * 256 + tid;                  // [0, 16*20*64)
        int ks   = idx / (NNT * 64);
        int rem  = idx % (NNT * 64);
        int nt   = rem / 64;
        int lane = rem % 64;
        int col  = nt * 16 + (lane & 15);
        int cl   = col / 20;
        int c    = col % 20;
        short8 sv;
#pragma unroll
        for (int j = 0; j < 8; ++j) {
            int k = ks * 32 + (lane >> 4) * 8 + j;
            float v;
            if (c < DLAT) v = Vs[(size_t)cl * DLAT * DAMB + c * DAMB + k];
            else          v = Us[(size_t)cl * DAMB * DLAT + k * DLAT + (c - DLAT)];
            sv[j] = f2bf(v);
        }
        *(short8*)&wpack[(size_t)idx * 8] = sv;
    } else {
        __shared__ float red[256];
        int k = b - 80;
        const float* Uk = Us + (size_t)k * DAMB * DLAT;
        const float* Vk = Vs + (size_t)k * DLAT * DAMB;
        float s = 0.f;
        for (int i = tid; i < DAMB * DLAT; i += 256) {
            float a = Uk[i], bb = Vk[i];
            s += a * a + bb * bb;
        }
        red[tid] = s;
        __syncthreads();
        for (int st = 128; st > 0; st >>= 1) {
            if (tid < st) red[tid] += red[tid + st];
            __syncthreads();
        }
        if (tid == 0) lreg[k] = LAMBDA * 0.5f * red[0];
        if (tid < DLAT * DLAT) {
            int i = tid / DLAT, j = tid % DLAT;
            float g = 0.f;
            for (int Dv = 0; Dv < DAMB; ++Dv)
                g += Uk[Dv * DLAT + i] * Uk[Dv * DLAT + j];
            G[k * 100 + tid] = g;
        }
    }
}

// raw global load the compiler cannot sink/merge
#define GLOAD(dst, addr) \
    asm volatile("global_load_dwordx4 %0, %1, off" : "=&v"(dst) : "v"(addr) : "memory")

template <int N> __device__ __forceinline__ void waitv() {
    if constexpr (N == 0)       asm volatile("s_waitcnt vmcnt(0)"  ::: "memory");
    else if constexpr (N == 5)  asm volatile("s_waitcnt vmcnt(5)"  ::: "memory");
    else if constexpr (N == 10) asm volatile("s_waitcnt vmcnt(10)" ::: "memory");
    else                        asm volatile("s_waitcnt vmcnt(15)" ::: "memory");
    __builtin_amdgcn_sched_barrier(0);   // rule #18: keep MFMAs below the wait
}

// ---------------- main kernel
__global__ __launch_bounds__(NTHREADS, 2) void main_k(const float* __restrict__ x,
                                                      const short* __restrict__ wpack,
                                                      const float* __restrict__ G,
                                                      const float* __restrict__ lreg,
                                                      float* __restrict__ parts,
                                                      unsigned* __restrict__ cnt,
                                                      float* __restrict__ out) {
    __shared__ __align__(16) char uni[BM * YS * 4];   // 41.6 KB: A frags, then Y
    __shared__ float Gs[KCLUST * 100];                // 6.4 KB
    __shared__ float lregs[KCLUST];
    __shared__ float rsqp[BM][8];
    __shared__ float rowsq_s[BM];
    __shared__ float objl[BM][17];
    __shared__ float red[NTHREADS];
    __shared__ int   isLast;

    short* a_lds = (short*)uni;                 // [mt][ks][lane][8], 32 KB
    float* y     = (float*)uni;                 // [BM][YS]

    const int tid  = threadIdx.x;
    const int lane = tid & 63;
    const int wv   = tid >> 6;                  // 0..3 = n-strip
    const int row0 = blockIdx.x * BM;

    // ---- stage A (fp32 -> bf16, fragment order) + exact fp32 rowsq; stage G
    {
        const int srow = tid >> 3;              // 0..31
        const int sc   = tid & 7;
        const int mt   = srow >> 4;
        const int rlo  = srow & 15;
        const float* xr = x + (size_t)(row0 + srow) * DAMB;
        float rs = 0.f;
#pragma unroll
        for (int i = 0; i < 8; ++i) {
            int k8 = sc + 8 * i;                // 0..63
            float4 v0 = *(const float4*)(xr + k8 * 8);
            float4 v1 = *(const float4*)(xr + k8 * 8 + 4);
            rs += v0.x * v0.x + v0.y * v0.y + v0.z * v0.z + v0.w * v0.w
                + v1.x * v1.x + v1.y * v1.y + v1.z * v1.z + v1.w * v1.w;
            short8 sv;
            sv[0] = f2bf(v0.x); sv[1] = f2bf(v0.y); sv[2] = f2bf(v0.z); sv[3] = f2bf(v0.w);
            sv[4] = f2bf(v1.x); sv[5] = f2bf(v1.y); sv[6] = f2bf(v1.z); sv[7] = f2bf(v1.w);
            int ks = k8 >> 2, lh = k8 & 3;
            int ln = (lh << 4) | rlo;
            *(short8*)&a_lds[((mt * NKS + ks) * 64 + ln) * 8] = sv;
        }
        rsqp[srow][sc] = rs;
    }
    for (int i = tid; i < KCLUST * 100; i += NTHREADS) Gs[i] = G[i];
    if (tid < KCLUST) lregs[tid] = lreg[tid];
    __syncthreads();                 // drains vmcnt to 0 before asm loads begin
    if (tid < BM) {
        float s = 0.f;
#pragma unroll
        for (int j = 0; j < 8; ++j) s += rsqp[tid][j];
        rowsq_s[tid] = s;
    }

    // ---- K loop: asm B loads, 4-deep group ring, counted vmcnt
    f32x4 acc[2][5];
#pragma unroll
    for (int m = 0; m < 2; ++m)
#pragma unroll
        for (int j = 0; j < 5; ++j) acc[m][j] = (f32x4)0.f;

    const char* wbase = (const char*)wpack + ((size_t)(wv * 5) * 64 + lane) * 16;
    short8 bb[4][5];

#define BADDR(ks, j) (wbase + (size_t)((ks) * 20480 + (j) * 1024))
#define LOADG(ks) do { \
        GLOAD(bb[(ks) & 3][0], BADDR(ks, 0)); \
        GLOAD(bb[(ks) & 3][1], BADDR(ks, 1)); \
        GLOAD(bb[(ks) & 3][2], BADDR(ks, 2)); \
        GLOAD(bb[(ks) & 3][3], BADDR(ks, 3)); \
        GLOAD(bb[(ks) & 3][4], BADDR(ks, 4)); \
    } while (0)

    LOADG(0); LOADG(1); LOADG(2); LOADG(3);

#define STEP(ks, VM) do { \
        short8 a0 = *(short8*)&a_lds[((0 * NKS + (ks)) * 64 + lane) * 8]; \
        short8 a1 = *(short8*)&a_lds[((1 * NKS + (ks)) * 64 + lane) * 8]; \
        waitv<VM>(); \
        acc[0][0] = __builtin_amdgcn_mfma_f32_16x16x32_bf16(a0, bb[(ks) & 3][0], acc[0][0], 0, 0, 0); \
        acc[1][0] = __builtin_amdgcn_mfma_f32_16x16x32_bf16(a1, bb[(ks) & 3][0], acc[1][0], 0, 0, 0); \
        acc[0][1] = __builtin_amdgcn_mfma_f32_16x16x32_bf16(a0, bb[(ks) & 3][1], acc[0][1], 0, 0, 0); \
        acc[1][1] = __builtin_amdgcn_mfma_f32_16x16x32_bf16(a1, bb[(ks) & 3][1], acc[1][1], 0, 0, 0); \
        acc[0][2] = __builtin_amdgcn_mfma_f32_16x16x32_bf16(a0, bb[(ks) & 3][2], acc[0][2], 0, 0, 0); \
        acc[1][2] = __builtin_amdgcn_mfma_f32_16x16x32_bf16(a1, bb[(ks) & 3][2], acc[1][2], 0, 0, 0); \
        acc[0][3] = __builtin_amdgcn_mfma_f32_16x16x32_bf16(a0, bb[(ks) & 3][3], acc[0][3], 0, 0, 0); \
        acc[1][3] = __builtin_amdgcn_mfma_f32_16x16x32_bf16(a1, bb[(ks) & 3][3], acc[1][3], 0, 0, 0); \
        acc[0][4] = __builtin_amdgcn_mfma_f32_16x16x32_bf16(a0, bb[(ks) & 3][4], acc[0][4], 0, 0, 0); \
        acc[1][4] = __builtin_amdgcn_mfma_f32_16x16x32_bf16(a1, bb[(ks) & 3][4], acc[1][4], 0, 0, 0); \
        if ((ks) + 4 < NKS) LOADG((ks) + 4); \
    } while (0)

    STEP(0, 15);  STEP(1, 15);  STEP(2, 15);  STEP(3, 15);
    STEP(4, 15);  STEP(5, 15);  STEP(6, 15);  STEP(7, 15);
    STEP(8, 15);  STEP(9, 15);  STEP(10, 15); STEP(11, 15);
    STEP(12, 15); STEP(13, 10); STEP(14, 5);  STEP(15, 0);

#undef STEP
#undef LOADG
#undef BADDR

    __syncthreads();                     // a_lds dead; uni becomes Y

    // ---- write Y tile. C/D layout: col = lane&15, row = (lane>>4)*4 + r
#pragma unroll
    for (int m = 0; m < 2; ++m) {
        int rowb = m * 16 + (lane >> 4) * 4;
#pragma unroll
        for (int j = 0; j < 5; ++j) {
            int colb = (wv * 5 + j) * 16 + (lane & 15);
#pragma unroll
            for (int r = 0; r < 4; ++r)
                y[(rowb + r) * YS + colb] = acc[m][j][r];
        }
    }
    __syncthreads();

    // ---- per-(row,k) objective; half-wave shares kk -> G broadcast reads
#pragma unroll
    for (int it = 0; it < 2; ++it) {
        int row = tid & 31;
        int kk  = (tid >> 5) + 8 * it;           // 0..15
        const float* yy = y + row * YS + kk * 20;
        float z[DLAT], w[DLAT];
#pragma unroll
        for (int i = 0; i < DLAT; ++i) { z[i] = yy[i]; w[i] = yy[DLAT + i]; }
        const float* Gk = Gs + kk * 100;
        float s = 0.f, wz = 0.f;
#pragma unroll
        for (int i = 0; i < DLAT; ++i) {
            float gz = 0.f;
#pragma unroll
            for (int j = 0; j < DLAT; ++j) gz = fmaf(Gk[i * DLAT + j], z[j], gz);
            s  = fmaf(z[i], gz, s);
            wz = fmaf(w[i], z[i], wz);
        }
        objl[row][kk] = s - 2.f * wz + lregs[kk];
    }
    __syncthreads();

    // ---- per-row min + wave-0 shuffle reduce
    if (wv == 0) {
        float v = 0.f;
        if (lane < BM) {
            float m = objl[lane][0];
#pragma unroll
            for (int k = 1; k < KCLUST; ++k) m = fminf(m, objl[lane][k]);
            v = m + rowsq_s[lane];
        }
#pragma unroll
        for (int off = 32; off > 0; off >>= 1) v += __shfl_down(v, off);
        if (lane == 0) {
            __hip_atomic_store(&parts[blockIdx.x], v, __ATOMIC_RELEASE,
                               __HIP_MEMORY_SCOPE_AGENT);
            unsigned prev = __hip_atomic_fetch_add(cnt, 1u, __ATOMIC_ACQ_REL,
                                                   __HIP_MEMORY_SCOPE_AGENT);
            isLast = (prev == NBLK - 1);
        }
    }
    __syncthreads();

    // ---- last block reduces all 512 partials (fixed-order tree => deterministic)
    if (isLast) {
        float s = __hip_atomic_load(&parts[tid], __ATOMIC_RELAXED, __HIP_MEMORY_SCOPE_AGENT)
                + __hip_atomic_load(&parts[tid + NTHREADS], __ATOMIC_RELAXED, __HIP_MEMORY_SCOPE_AGENT);
        red[tid] = s;
        __syncthreads();
        for (int st = NTHREADS / 2; st > 0; st >>= 1) {
            if (tid < st) red[tid] += red[tid + st];
            __syncthreads();
        }
        if (tid == 0) out[0] = red[0] * (1.0f / BATCH);
    }
}

extern "C" void kernel_launch(void* const* d_in, const int* in_sizes, int n_in,
                              void* d_out, int out_size, void* d_ws, size_t ws_size,
                              hipStream_t stream) {
    const float* x  = (const float*)d_in[0];   // 16384 x 512
    const float* Us = (const float*)d_in[1];   // 16 x 512 x 10
    const float* Vs = (const float*)d_in[2];   // 16 x 10 x 512
    float* out = (float*)d_out;

    // workspace: wpack[20480*8] shorts (320KB) | G[1600] | lreg[16] | parts[512] | cnt
    short* wpack   = (short*)d_ws;
    float* G       = (float*)(wpack + NKS * NNT * 64 * 8);
    float* lreg    = G + KCLUST * 100;
    float* parts   = lreg + KCLUST;
    unsigned* cnt  = (unsigned*)(parts + NBLK);

    setup_k<<<96, 256, 0, stream>>>(Us, Vs, wpack, G, lreg, cnt);
    main_k<<<NBLK, NTHREADS, 0, stream>>>(x, wpack, G, lreg, parts, cnt, out);
}

// Round 9
// 44.775 us; speedup vs baseline: 1.4601x; 1.0864x over previous
//
#include <hip/hip_runtime.h>

// K-manifold AE cluster objective, fused, bf16-MFMA GEMM.
// out = mean_b min_k [ ||x_b||^2 - 2 w.z + z^T G z + lamb*reg_k ]
// GEMM: Y[16384][320] = X[16384][512] @ W[512][320] via pre-packed B fragments.
// Round 9: BM=128 (4x less W replication: 41MB), 128 blocks, asm vmcnt ring,
// wave-local epilogue (5 n-tiles = 4 clusters per wave, no Y materialization).

#define KCLUST   16
#define DAMB     512
#define DLAT     10
#define BATCH    16384
#define NC       320
#define LAMBDA   0.01f

#define BM       128           // batch rows per block (8 m-tiles)
#define NTHREADS 512           // 8 waves: 2M x 4N
#define NKS      16            // 512/32 k-steps
#define NNT      20            // 320/16 n-tiles
#define NBLK     (BATCH / BM)  // 128
#define SSTR     84            // epilogue strip stride (floats)

typedef __attribute__((ext_vector_type(8))) short short8;
typedef __attribute__((ext_vector_type(4))) float f32x4;

__device__ inline short f2bf(float f) {
    unsigned u = __builtin_bit_cast(unsigned, f);
    unsigned r = (u + 0x7FFFu + ((u >> 16) & 1u)) >> 16;
    return (short)r;
}

// ---------------- setup: blocks 0..79 pack W frags; 80..95 compute G/lreg; zero cnt
// wpack[ks][nt][lane][8]: lane l holds B[k = ks*32 + (l>>4)*8 + j][col = nt*16 + (l&15)]
__global__ __launch_bounds__(256) void setup_k(const float* __restrict__ Us,
                                               const float* __restrict__ Vs,
                                               short* __restrict__ wpack,
                                               float* __restrict__ G,
                                               float* __restrict__ lreg,
                                               unsigned* __restrict__ cnt) {
    int b = blockIdx.x;
    int tid = threadIdx.x;
    if (b == 0 && tid == 0)
        __hip_atomic_store(cnt, 0u, __ATOMIC_RELEASE, __HIP_MEMORY_SCOPE_AGENT);
    if (b < 80) {
        int idx  = b * 256 + tid;                  // [0, 16*20*64)
        int ks   = idx / (NNT * 64);
        int rem  = idx % (NNT * 64);
        int nt   = rem / 64;
        int lane = rem % 64;
        int col  = nt * 16 + (lane & 15);
        int cl   = col / 20;
        int c    = col % 20;
        short8 sv;
#pragma unroll
        for (int j = 0; j < 8; ++j) {
            int k = ks * 32 + (lane >> 4) * 8 + j;
            float v;
            if (c < DLAT) v = Vs[(size_t)cl * DLAT * DAMB + c * DAMB + k];
            else          v = Us[(size_t)cl * DAMB * DLAT + k * DLAT + (c - DLAT)];
            sv[j] = f2bf(v);
        }
        *(short8*)&wpack[(size_t)idx * 8] = sv;
    } else {
        __shared__ float red[256];
        int k = b - 80;
        const float* Uk = Us + (size_t)k * DAMB * DLAT;
        const float* Vk = Vs + (size_t)k * DLAT * DAMB;
        float s = 0.f;
        for (int i = tid; i < DAMB * DLAT; i += 256) {
            float a = Uk[i], bb = Vk[i];
            s += a * a + bb * bb;
        }
        red[tid] = s;
        __syncthreads();
        for (int st = 128; st > 0; st >>= 1) {
            if (tid < st) red[tid] += red[tid + st];
            __syncthreads();
        }
        if (tid == 0) lreg[k] = LAMBDA * 0.5f * red[0];
        if (tid < DLAT * DLAT) {
            int i = tid / DLAT, j = tid % DLAT;
            float g = 0.f;
            for (int Dv = 0; Dv < DAMB; ++Dv)
                g += Uk[Dv * DLAT + i] * Uk[Dv * DLAT + j];
            G[k * 100 + tid] = g;
        }
    }
}

// raw global load the compiler cannot sink/merge
#define GLOAD(dst, addr) \
    asm volatile("global_load_dwordx4 %0, %1, off" : "=&v"(dst) : "v"(addr) : "memory")

template <int N> __device__ __forceinline__ void waitv() {
    if constexpr (N == 0)       asm volatile("s_waitcnt vmcnt(0)"  ::: "memory");
    else if constexpr (N == 5)  asm volatile("s_waitcnt vmcnt(5)"  ::: "memory");
    else if constexpr (N == 10) asm volatile("s_waitcnt vmcnt(10)" ::: "memory");
    else                        asm volatile("s_waitcnt vmcnt(15)" ::: "memory");
    __builtin_amdgcn_sched_barrier(0);   // rule #18: keep MFMAs below the wait
}

// ---------------- main kernel
__global__ __launch_bounds__(NTHREADS, 2) void main_k(const float* __restrict__ x,
                                                      const short* __restrict__ wpack,
                                                      const float* __restrict__ G,
                                                      const float* __restrict__ lreg,
                                                      float* __restrict__ parts,
                                                      unsigned* __restrict__ cnt,
                                                      float* __restrict__ out) {
    __shared__ __align__(16) char uni[128 * 1024];    // A frags; later per-wave strips
    __shared__ float Gs[KCLUST * 100];                // 6.4 KB
    __shared__ float lregs[KCLUST];
    __shared__ float rsqp[BM][4];
    __shared__ float rowsq_s[BM];
    __shared__ float objl[BM][17];
    __shared__ float red[BM];
    __shared__ int   isLast;

    short* a_lds = (short*)uni;                 // [mt 0..7][ks][lane][8], 128 KB
    float* sbuf  = (float*)uni;                 // [wave][32][SSTR]

    const int tid  = threadIdx.x;
    const int lane = tid & 63;
    const int wv   = tid >> 6;                  // 0..7
    const int mw   = wv >> 2;                   // 0..1: m-tiles mw*4 .. +3
    const int nw   = wv & 3;                    // 0..3: n-tiles nw*5 .. +4
    const int row0 = blockIdx.x * BM;

    // ---- stage A (fp32 -> bf16, fragment order) + exact fp32 rowsq; stage G
    {
        const int srow = tid >> 2;              // 0..127
        const int sc   = tid & 3;               // 0..3
        const int mt   = srow >> 4;
        const int rlo  = srow & 15;
        const float* xr = x + (size_t)(row0 + srow) * DAMB;
        float rs = 0.f;
#pragma unroll
        for (int i = 0; i < 16; ++i) {
            int k8 = sc + 4 * i;                // 8-float group, 0..63
            float4 v0 = *(const float4*)(xr + k8 * 8);
            float4 v1 = *(const float4*)(xr + k8 * 8 + 4);
            rs += v0.x * v0.x + v0.y * v0.y + v0.z * v0.z + v0.w * v0.w
                + v1.x * v1.x + v1.y * v1.y + v1.z * v1.z + v1.w * v1.w;
            short8 sv;
            sv[0] = f2bf(v0.x); sv[1] = f2bf(v0.y); sv[2] = f2bf(v0.z); sv[3] = f2bf(v0.w);
            sv[4] = f2bf(v1.x); sv[5] = f2bf(v1.y); sv[6] = f2bf(v1.z); sv[7] = f2bf(v1.w);
            int ks = k8 >> 2, lh = k8 & 3;
            int ln = (lh << 4) | rlo;
            *(short8*)&a_lds[((mt * NKS + ks) * 64 + ln) * 8] = sv;
        }
        rsqp[srow][sc] = rs;
    }
    for (int i = tid; i < KCLUST * 100; i += NTHREADS) Gs[i] = G[i];
    if (tid < KCLUST) lregs[tid] = lreg[tid];
    __syncthreads();                 // drains vmcnt to 0 before asm loads begin
    if (tid < BM)
        rowsq_s[tid] = rsqp[tid][0] + rsqp[tid][1] + rsqp[tid][2] + rsqp[tid][3];

    // ---- K loop: asm B loads, 4-deep group ring, counted vmcnt
    f32x4 acc[4][5];
#pragma unroll
    for (int m = 0; m < 4; ++m)
#pragma unroll
        for (int j = 0; j < 5; ++j) acc[m][j] = (f32x4)0.f;

    const char* wbase = (const char*)wpack + ((size_t)(nw * 5) * 64 + lane) * 16;
    short8 bb[4][5];

#define BADDR(ks, j) (wbase + (size_t)((ks) * 20480 + (j) * 1024))
#define LOADG(ks) do { \
        GLOAD(bb[(ks) & 3][0], BADDR(ks, 0)); \
        GLOAD(bb[(ks) & 3][1], BADDR(ks, 1)); \
        GLOAD(bb[(ks) & 3][2], BADDR(ks, 2)); \
        GLOAD(bb[(ks) & 3][3], BADDR(ks, 3)); \
        GLOAD(bb[(ks) & 3][4], BADDR(ks, 4)); \
    } while (0)

    LOADG(0); LOADG(1); LOADG(2); LOADG(3);

#define STEP(ks, VM) do { \
        short8 a0 = *(short8*)&a_lds[(((mw * 4 + 0) * NKS + (ks)) * 64 + lane) * 8]; \
        short8 a1 = *(short8*)&a_lds[(((mw * 4 + 1) * NKS + (ks)) * 64 + lane) * 8]; \
        short8 a2 = *(short8*)&a_lds[(((mw * 4 + 2) * NKS + (ks)) * 64 + lane) * 8]; \
        short8 a3 = *(short8*)&a_lds[(((mw * 4 + 3) * NKS + (ks)) * 64 + lane) * 8]; \
        waitv<VM>(); \
        acc[0][0] = __builtin_amdgcn_mfma_f32_16x16x32_bf16(a0, bb[(ks) & 3][0], acc[0][0], 0, 0, 0); \
        acc[1][0] = __builtin_amdgcn_mfma_f32_16x16x32_bf16(a1, bb[(ks) & 3][0], acc[1][0], 0, 0, 0); \
        acc[2][0] = __builtin_amdgcn_mfma_f32_16x16x32_bf16(a2, bb[(ks) & 3][0], acc[2][0], 0, 0, 0); \
        acc[3][0] = __builtin_amdgcn_mfma_f32_16x16x32_bf16(a3, bb[(ks) & 3][0], acc[3][0], 0, 0, 0); \
        acc[0][1] = __builtin_amdgcn_mfma_f32_16x16x32_bf16(a0, bb[(ks) & 3][1], acc[0][1], 0, 0, 0); \
        acc[1][1] = __builtin_amdgcn_mfma_f32_16x16x32_bf16(a1, bb[(ks) & 3][1], acc[1][1], 0, 0, 0); \
        acc[2][1] = __builtin_amdgcn_mfma_f32_16x16x32_bf16(a2, bb[(ks) & 3][1], acc[2][1], 0, 0, 0); \
        acc[3][1] = __builtin_amdgcn_mfma_f32_16x16x32_bf16(a3, bb[(ks) & 3][1], acc[3][1], 0, 0, 0); \
        acc[0][2] = __builtin_amdgcn_mfma_f32_16x16x32_bf16(a0, bb[(ks) & 3][2], acc[0][2], 0, 0, 0); \
        acc[1][2] = __builtin_amdgcn_mfma_f32_16x16x32_bf16(a1, bb[(ks) & 3][2], acc[1][2], 0, 0, 0); \
        acc[2][2] = __builtin_amdgcn_mfma_f32_16x16x32_bf16(a2, bb[(ks) & 3][2], acc[2][2], 0, 0, 0); \
        acc[3][2] = __builtin_amdgcn_mfma_f32_16x16x32_bf16(a3, bb[(ks) & 3][2], acc[3][2], 0, 0, 0); \
        acc[0][3] = __builtin_amdgcn_mfma_f32_16x16x32_bf16(a0, bb[(ks) & 3][3], acc[0][3], 0, 0, 0); \
        acc[1][3] = __builtin_amdgcn_mfma_f32_16x16x32_bf16(a1, bb[(ks) & 3][3], acc[1][3], 0, 0, 0); \
        acc[2][3] = __builtin_amdgcn_mfma_f32_16x16x32_bf16(a2, bb[(ks) & 3][3], acc[2][3], 0, 0, 0); \
        acc[3][3] = __builtin_amdgcn_mfma_f32_16x16x32_bf16(a3, bb[(ks) & 3][3], acc[3][3], 0, 0, 0); \
        acc[0][4] = __builtin_amdgcn_mfma_f32_16x16x32_bf16(a0, bb[(ks) & 3][4], acc[0][4], 0, 0, 0); \
        acc[1][4] = __builtin_amdgcn_mfma_f32_16x16x32_bf16(a1, bb[(ks) & 3][4], acc[1][4], 0, 0, 0); \
        acc[2][4] = __builtin_amdgcn_mfma_f32_16x16x32_bf16(a2, bb[(ks) & 3][4], acc[2][4], 0, 0, 0); \
        acc[3][4] = __builtin_amdgcn_mfma_f32_16x16x32_bf16(a3, bb[(ks) & 3][4], acc[3][4], 0, 0, 0); \
        if ((ks) + 4 < NKS) LOADG((ks) + 4); \
    } while (0)

    STEP(0, 15);  STEP(1, 15);  STEP(2, 15);  STEP(3, 15);
    STEP(4, 15);  STEP(5, 15);  STEP(6, 15);  STEP(7, 15);
    STEP(8, 15);  STEP(9, 15);  STEP(10, 15); STEP(11, 15);
    STEP(12, 15); STEP(13, 10); STEP(14, 5);  STEP(15, 0);

#undef STEP
#undef LOADG
#undef BADDR

    __syncthreads();                     // a_lds dead; uni becomes per-wave strips

    // ---- epilogue, wave-local: wave (mw,nw) owns rows mw*64..+63, clusters nw*4..+3
    const int sboff = wv * (32 * SSTR);
#pragma unroll
    for (int mh = 0; mh < 2; ++mh) {
        // write half of this wave's acc into its private strip [32][SSTR]
#pragma unroll
        for (int qq = 0; qq < 2; ++qq) {
            int q = mh * 2 + qq;
            int rowl = qq * 16 + (lane >> 4) * 4;
#pragma unroll
            for (int j = 0; j < 5; ++j) {
                int coll = j * 16 + (lane & 15);
#pragma unroll
                for (int r = 0; r < 4; ++r)
                    sbuf[sboff + (rowl + r) * SSTR + coll] = acc[q][j][r];
            }
        }
        __syncthreads();                 // cross-lane strip visibility
        // objective for 32 rows x 4 clusters, 2 items/lane
#pragma unroll
        for (int it = 0; it < 2; ++it) {
            int i = lane + 64 * it;
            int rowl = i >> 2, cl = i & 3;
            const float* yy = sbuf + sboff + rowl * SSTR + cl * 20;
            float4 v0 = *(const float4*)(yy + 0);
            float4 v1 = *(const float4*)(yy + 4);
            float4 v2 = *(const float4*)(yy + 8);
            float4 v3 = *(const float4*)(yy + 12);
            float4 v4 = *(const float4*)(yy + 16);
            float z[DLAT] = {v0.x, v0.y, v0.z, v0.w, v1.x, v1.y, v1.z, v1.w, v2.x, v2.y};
            float w[DLAT] = {v2.z, v2.w, v3.x, v3.y, v3.z, v3.w, v4.x, v4.y, v4.z, v4.w};
            int kk = nw * 4 + cl;
            const float* Gk = Gs + kk * 100;
            float s = 0.f, wz = 0.f;
#pragma unroll
            for (int a = 0; a < DLAT; ++a) {
                float gz = 0.f;
#pragma unroll
                for (int b2 = 0; b2 < DLAT; ++b2) gz = fmaf(Gk[a * DLAT + b2], z[b2], gz);
                s  = fmaf(z[a], gz, s);
                wz = fmaf(w[a], z[a], wz);
            }
            objl[mw * 64 + mh * 32 + rowl][kk] = s - 2.f * wz + lregs[kk];
        }
        __syncthreads();                 // strip reads done before next half's writes
    }

    // ---- per-row min + reduce
    if (tid < BM) {
        float m = objl[tid][0];
#pragma unroll
        for (int k = 1; k < KCLUST; ++k) m = fminf(m, objl[tid][k]);
        red[tid] = m + rowsq_s[tid];
    }
    __syncthreads();
    if (wv == 0) {
        float v = red[lane] + red[lane + 64];
#pragma unroll
        for (int off = 32; off > 0; off >>= 1) v += __shfl_down(v, off);
        if (lane == 0) {
            __hip_atomic_store(&parts[blockIdx.x], v, __ATOMIC_RELEASE,
                               __HIP_MEMORY_SCOPE_AGENT);
            unsigned prev = __hip_atomic_fetch_add(cnt, 1u, __ATOMIC_ACQ_REL,
                                                   __HIP_MEMORY_SCOPE_AGENT);
            isLast = (prev == NBLK - 1);
        }
    }
    __syncthreads();

    // ---- last block reduces all 128 partials (fixed-order => deterministic)
    if (isLast && wv == 0) {
        float s = __hip_atomic_load(&parts[lane], __ATOMIC_RELAXED, __HIP_MEMORY_SCOPE_AGENT)
                + __hip_atomic_load(&parts[lane + 64], __ATOMIC_RELAXED, __HIP_MEMORY_SCOPE_AGENT);
#pragma unroll
        for (int off = 32; off > 0; off >>= 1) s += __shfl_down(s, off);
        if (lane == 0) out[0] = s * (1.0f / BATCH);
    }
}

extern "C" void kernel_launch(void* const* d_in, const int* in_sizes, int n_in,
                              void* d_out, int out_size, void* d_ws, size_t ws_size,
                              hipStream_t stream) {
    const float* x  = (const float*)d_in[0];   // 16384 x 512
    const float* Us = (const float*)d_in[1];   // 16 x 512 x 10
    const float* Vs = (const float*)d_in[2];   // 16 x 10 x 512
    float* out = (float*)d_out;

    // workspace: wpack[20480*8] shorts (320KB) | G[1600] | lreg[16] | parts[128] | cnt
    short* wpack   = (short*)d_ws;
    float* G       = (float*)(wpack + NKS * NNT * 64 * 8);
    float* lreg    = G + KCLUST * 100;
    float* parts   = lreg + KCLUST;
    unsigned* cnt  = (unsigned*)(parts + NBLK);

    setup_k<<<96, 256, 0, stream>>>(Us, Vs, wpack, G, lreg, cnt);
    main_k<<<NBLK, NTHREADS, 0, stream>>>(x, wpack, G, lreg, parts, cnt, out);
}